// Round 1
// baseline (641.155 us; speedup 1.0000x reference)
//
#include <hip/hip_runtime.h>

typedef float f32x4 __attribute__((ext_vector_type(4)));
typedef short s16x8 __attribute__((ext_vector_type(8)));
typedef short s16x4 __attribute__((ext_vector_type(4)));

#define DEVI __device__ __forceinline__

static constexpr int B_ = 4, T_ = 4096, D_ = 2048, E_ = 8, C_ = 512, O_ = 2048, I_ = 256;

DEVI short f2bf(float f) {
  unsigned u = __builtin_bit_cast(unsigned, f);
  u += 0x7FFFu + ((u >> 16) & 1u);
  return (short)(u >> 16);
}

// ---------------------------------------------------------------------------
// Kernel 0: w[e][o][i] f32 -> wT[o][e*256+i] bf16
// ---------------------------------------------------------------------------
__global__ __launch_bounds__(256) void k_prep_wT(const float* __restrict__ w,
                                                 short* __restrict__ wT) {
  int idx = blockIdx.x * 256 + threadIdx.x;      // one per 4 elements, [0, 1M)
  int o  = idx >> 9;                             // 512 quads per o-row
  int dd = (idx & 511) << 2;                     // d = e*256+i
  int e = dd >> 8, i = dd & 255;
  f32x4 v = *(const f32x4*)(w + (((size_t)e * O_ + o) * I_ + i));
  s16x4 p;
#pragma unroll
  for (int j = 0; j < 4; j++) p[j] = f2bf(v[j]);
  *(s16x4*)(wT + (size_t)o * D_ + dd) = p;
}

// ---------------------------------------------------------------------------
// Kernel 1: xdT[b,e][i][c] = sum_t x[b,t,e*256+i] * disp[b,t,e,c]   (bf16 out)
// Both operands K(t)-slow: LDS tiles stored [t][col] (global orientation),
// fragments gathered via 8x ds_read_u16 with group swizzle.
// Tile: 128(i) x 128(c), BK=64(t). Grid: 32 (b,e) x (2 mt x 4 nt) = 256.
// ---------------------------------------------------------------------------
__global__ __launch_bounds__(256) void k_gemm1(const float* __restrict__ x,
                                               const float* __restrict__ disp,
                                               short* __restrict__ xdT) {
  __shared__ short lX[64 * 128];
  __shared__ short lD[64 * 128];
  const int tid = threadIdx.x;
  const int bid = blockIdx.x;
  const int be = bid >> 3, tile = bid & 7;
  const int mt = tile >> 2, nt = tile & 3;
  const int b = be >> 3, e = be & 7;
  const int lane = tid & 63, wid = tid >> 6;
  const int wm = wid >> 1, wn = wid & 1;
  const int g = lane >> 4, lr = lane & 15;

  const size_t xbase = (size_t)b * T_ * D_ + (size_t)e * I_ + (size_t)mt * 128;
  const size_t dbase = (size_t)b * T_ * (E_ * C_) + (size_t)e * C_ + (size_t)nt * 128;

  const f32x4 z4 = {0.f, 0.f, 0.f, 0.f};
  f32x4 acc[4][4];
#pragma unroll
  for (int i = 0; i < 4; i++)
#pragma unroll
    for (int j = 0; j < 4; j++) acc[i][j] = z4;

  for (int kt = 0; kt < T_; kt += 64) {
    __syncthreads();
#pragma unroll
    for (int cc = 0; cc < 4; cc++) {
      const int q = tid + 256 * cc;
      const int tr = q >> 4;               // 0..63  (t within tile)
      const int i8 = (q & 15) << 3;        // 0..120 (col chunk)
      const int sw = ((tr >> 3) & 3) << 4; // ushort-index XOR, bits 4-5
      const float* sx = x + xbase + (size_t)(kt + tr) * D_ + i8;
      f32x4 a0 = *(const f32x4*)sx;
      f32x4 a1 = *(const f32x4*)(sx + 4);
      s16x8 pa;
#pragma unroll
      for (int j = 0; j < 4; j++) { pa[j] = f2bf(a0[j]); pa[4 + j] = f2bf(a1[j]); }
      *(s16x8*)&lX[tr * 128 + (i8 ^ sw)] = pa;
      const float* sd = disp + dbase + (size_t)(kt + tr) * (E_ * C_) + i8;
      f32x4 d0 = *(const f32x4*)sd;
      f32x4 d1 = *(const f32x4*)(sd + 4);
      s16x8 pd;
#pragma unroll
      for (int j = 0; j < 4; j++) { pd[j] = f2bf(d0[j]); pd[4 + j] = f2bf(d1[j]); }
      *(s16x8*)&lD[tr * 128 + (i8 ^ sw)] = pd;
    }
    __syncthreads();
#pragma unroll
    for (int kk = 0; kk < 2; kk++) {
      const int tb = kk * 32 + g * 8;        // this lane's k(t) base
      const int sw = ((tb >> 3) & 3) << 4;   // constant over j (tb mult of 8)
      s16x8 af[4], bf[4];
#pragma unroll
      for (int mi = 0; mi < 4; mi++) {
        const int base = tb * 128 + ((wm * 64 + mi * 16 + lr) ^ sw);
        s16x8 a;
#pragma unroll
        for (int j = 0; j < 8; j++) a[j] = lX[base + 128 * j];
        af[mi] = a;
      }
#pragma unroll
      for (int ni = 0; ni < 4; ni++) {
        const int base = tb * 128 + ((wn * 64 + ni * 16 + lr) ^ sw);
        s16x8 bb;
#pragma unroll
        for (int j = 0; j < 8; j++) bb[j] = lD[base + 128 * j];
        bf[ni] = bb;
      }
#pragma unroll
      for (int mi = 0; mi < 4; mi++)
#pragma unroll
        for (int ni = 0; ni < 4; ni++)
          acc[mi][ni] = __builtin_amdgcn_mfma_f32_16x16x32_bf16(af[mi], bf[ni], acc[mi][ni], 0, 0, 0);
    }
  }
  short* op = xdT + (size_t)be * I_ * C_;
#pragma unroll
  for (int mi = 0; mi < 4; mi++)
#pragma unroll
    for (int ni = 0; ni < 4; ni++)
#pragma unroll
      for (int r = 0; r < 4; r++) {
        const int ig = mt * 128 + wm * 64 + mi * 16 + g * 4 + r;
        const int cg = nt * 128 + wn * 64 + ni * 16 + lr;
        op[(size_t)ig * C_ + cg] = f2bf(acc[mi][ni][r]);
      }
}

// ---------------------------------------------------------------------------
// Kernel 2: z[b][t][e*256+i] = sum_c comb[b,t,e,c] * xdT[b,e][i][c]  (bf16)
// Also (nt==0 blocks): Se[b,e,t] = sum_c comb[b,t,e,c]  (f32, pre-cvt values)
// Tile 128(t) x 128(i), BK=64(c). Grid: 32 (b,e) x (32 mt x 2 nt) = 2048.
// ---------------------------------------------------------------------------
__global__ __launch_bounds__(256) void k_zgemm(const float* __restrict__ comb,
                                               const short* __restrict__ xdT,
                                               short* __restrict__ z,
                                               float* __restrict__ Se) {
  __shared__ short lA[128 * 64];
  __shared__ short lB[128 * 64];
  const int tid = threadIdx.x;
  const int bid = blockIdx.x;
  const int be = bid >> 6, rest = bid & 63;
  const int mt = rest >> 1, nt = rest & 1;
  const int b = be >> 3, e = be & 7;
  const int lane = tid & 63, wid = tid >> 6;
  const int wm = wid >> 1, wn = wid & 1;
  const int g = lane >> 4, lr = lane & 15;

  const size_t abase = (size_t)b * T_ * (E_ * C_) + (size_t)(mt * 128) * (E_ * C_) + (size_t)e * C_;
  const short* Bsrc = xdT + (size_t)be * I_ * C_ + (size_t)(nt * 128) * C_;

  float rs[4] = {0.f, 0.f, 0.f, 0.f};
  const f32x4 z4 = {0.f, 0.f, 0.f, 0.f};
  f32x4 acc[4][4];
#pragma unroll
  for (int i = 0; i < 4; i++)
#pragma unroll
    for (int j = 0; j < 4; j++) acc[i][j] = z4;

  for (int ct = 0; ct < C_; ct += 64) {
    __syncthreads();
#pragma unroll
    for (int cc = 0; cc < 4; cc++) {
      const int q = tid + 256 * cc;
      const int row = q >> 3;           // 0..127
      const int k8 = (q & 7) << 3;      // 0..56
      const int sw = (row & 7) << 3;    // T2 swizzle (byte<<4 == ushort<<3)
      const float* sa = comb + abase + (size_t)row * (E_ * C_) + ct + k8;
      f32x4 a0 = *(const f32x4*)sa;
      f32x4 a1 = *(const f32x4*)(sa + 4);
      rs[cc] += a0[0] + a0[1] + a0[2] + a0[3] + a1[0] + a1[1] + a1[2] + a1[3];
      s16x8 pa;
#pragma unroll
      for (int j = 0; j < 4; j++) { pa[j] = f2bf(a0[j]); pa[4 + j] = f2bf(a1[j]); }
      *(s16x8*)&lA[row * 64 + (k8 ^ sw)] = pa;
      s16x8 pb = *(const s16x8*)(Bsrc + (size_t)row * C_ + ct + k8);
      *(s16x8*)&lB[row * 64 + (k8 ^ sw)] = pb;
    }
    __syncthreads();
#pragma unroll
    for (int kk = 0; kk < 2; kk++) {
      const int kb = kk * 32 + g * 8;
      s16x8 af[4], bf[4];
#pragma unroll
      for (int mi = 0; mi < 4; mi++) {
        const int r = wm * 64 + mi * 16 + lr;
        af[mi] = *(const s16x8*)&lA[r * 64 + (kb ^ ((r & 7) << 3))];
      }
#pragma unroll
      for (int ni = 0; ni < 4; ni++) {
        const int r = wn * 64 + ni * 16 + lr;
        bf[ni] = *(const s16x8*)&lB[r * 64 + (kb ^ ((r & 7) << 3))];
      }
#pragma unroll
      for (int mi = 0; mi < 4; mi++)
#pragma unroll
        for (int ni = 0; ni < 4; ni++)
          acc[mi][ni] = __builtin_amdgcn_mfma_f32_16x16x32_bf16(af[mi], bf[ni], acc[mi][ni], 0, 0, 0);
    }
  }
  if (nt == 0) {
#pragma unroll
    for (int cc = 0; cc < 4; cc++) {
      float v = rs[cc];
      v += __shfl_xor(v, 1);
      v += __shfl_xor(v, 2);
      v += __shfl_xor(v, 4);
      if ((tid & 7) == 0)
        Se[((size_t)b * E_ + e) * T_ + mt * 128 + (tid >> 3) + 32 * cc] = v;
    }
  }
#pragma unroll
  for (int mi = 0; mi < 4; mi++)
#pragma unroll
    for (int ni = 0; ni < 4; ni++)
#pragma unroll
      for (int r = 0; r < 4; r++) {
        const int tg = mt * 128 + wm * 64 + mi * 16 + g * 4 + r;
        const int ig = nt * 128 + wn * 64 + ni * 16 + lr;
        z[((size_t)b * T_ + tg) * D_ + e * I_ + ig] = f2bf(acc[mi][ni][r]);
      }
}

// ---------------------------------------------------------------------------
// Kernel 3: S[b,t] = sum_e Se[b,e,t]
// ---------------------------------------------------------------------------
__global__ __launch_bounds__(256) void k_reduceS(const float* __restrict__ Se,
                                                 float* __restrict__ S) {
  int idx = blockIdx.x * 256 + threadIdx.x;  // [0, B*T)
  int b = idx >> 12, t = idx & (T_ - 1);
  float s = 0.f;
#pragma unroll
  for (int e = 0; e < E_; e++) s += Se[((size_t)b * E_ + e) * T_ + t];
  S[idx] = s;
}

// ---------------------------------------------------------------------------
// Kernel 4: out[b][t][o] = sum_d z[b][t][d]*wT[o][d] + bias[o]*S[b,t]  (f32)
// Tile 128(t) x 128(o), BK=64(d). Grid: 4 b x (32 mt x 16 nt) = 2048.
// ---------------------------------------------------------------------------
__global__ __launch_bounds__(256) void k_outgemm(const short* __restrict__ z,
                                                 const short* __restrict__ wT,
                                                 const float* __restrict__ bias,
                                                 const float* __restrict__ S,
                                                 float* __restrict__ out) {
  __shared__ short lA[128 * 64];
  __shared__ short lB[128 * 64];
  const int tid = threadIdx.x;
  const int bid = blockIdx.x;
  const int b = bid >> 9, rest = bid & 511;
  const int mt = rest >> 4, nt = rest & 15;
  const int lane = tid & 63, wid = tid >> 6;
  const int wm = wid >> 1, wn = wid & 1;
  const int g = lane >> 4, lr = lane & 15;

  const short* Asrc = z + ((size_t)b * T_ + mt * 128) * D_;
  const short* Bsrc = wT + (size_t)(nt * 128) * D_;

  const f32x4 z4 = {0.f, 0.f, 0.f, 0.f};
  f32x4 acc[4][4];
#pragma unroll
  for (int i = 0; i < 4; i++)
#pragma unroll
    for (int j = 0; j < 4; j++) acc[i][j] = z4;

  for (int dt = 0; dt < D_; dt += 64) {
    __syncthreads();
#pragma unroll
    for (int cc = 0; cc < 4; cc++) {
      const int q = tid + 256 * cc;
      const int row = q >> 3;
      const int k8 = (q & 7) << 3;
      const int sw = (row & 7) << 3;
      s16x8 pa = *(const s16x8*)(Asrc + (size_t)row * D_ + dt + k8);
      *(s16x8*)&lA[row * 64 + (k8 ^ sw)] = pa;
      s16x8 pb = *(const s16x8*)(Bsrc + (size_t)row * D_ + dt + k8);
      *(s16x8*)&lB[row * 64 + (k8 ^ sw)] = pb;
    }
    __syncthreads();
#pragma unroll
    for (int kk = 0; kk < 2; kk++) {
      const int kb = kk * 32 + g * 8;
      s16x8 af[4], bf[4];
#pragma unroll
      for (int mi = 0; mi < 4; mi++) {
        const int r = wm * 64 + mi * 16 + lr;
        af[mi] = *(const s16x8*)&lA[r * 64 + (kb ^ ((r & 7) << 3))];
      }
#pragma unroll
      for (int ni = 0; ni < 4; ni++) {
        const int r = wn * 64 + ni * 16 + lr;
        bf[ni] = *(const s16x8*)&lB[r * 64 + (kb ^ ((r & 7) << 3))];
      }
#pragma unroll
      for (int mi = 0; mi < 4; mi++)
#pragma unroll
        for (int ni = 0; ni < 4; ni++)
          acc[mi][ni] = __builtin_amdgcn_mfma_f32_16x16x32_bf16(af[mi], bf[ni], acc[mi][ni], 0, 0, 0);
    }
  }
  float bia[4];
#pragma unroll
  for (int ni = 0; ni < 4; ni++) bia[ni] = bias[nt * 128 + wn * 64 + ni * 16 + lr];
#pragma unroll
  for (int mi = 0; mi < 4; mi++)
#pragma unroll
    for (int r = 0; r < 4; r++) {
      const int tg = mt * 128 + wm * 64 + mi * 16 + g * 4 + r;
      const float s = S[(size_t)b * T_ + tg];
#pragma unroll
      for (int ni = 0; ni < 4; ni++) {
        const int og = nt * 128 + wn * 64 + ni * 16 + lr;
        out[((size_t)b * T_ + tg) * O_ + og] = acc[mi][ni][r] + bia[ni] * s;
      }
    }
}

// ---------------------------------------------------------------------------
extern "C" void kernel_launch(void* const* d_in, const int* in_sizes, int n_in,
                              void* d_out, int out_size, void* d_ws, size_t ws_size,
                              hipStream_t stream) {
  const float* x    = (const float*)d_in[0];
  const float* comb = (const float*)d_in[1];
  const float* disp = (const float*)d_in[2];
  const float* w    = (const float*)d_in[3];
  const float* bias = (const float*)d_in[4];
  float* out = (float*)d_out;

  char* ws = (char*)d_ws;
  short* wT  = (short*)(ws);                    //  8,388,608 B  [O][D] bf16
  short* xdT = (short*)(ws + 8388608);          //  8,388,608 B  [B,E][I][C] bf16
  short* z   = (short*)(ws + 16777216);         // 67,108,864 B  [B][T][D] bf16
  float* Se  = (float*)(ws + 83886080);         //    524,288 B  [B][E][T] f32
  float* S   = (float*)(ws + 84410368);         //     65,536 B  [B][T] f32

  k_prep_wT<<<dim3(4096), dim3(256), 0, stream>>>(w, wT);
  k_gemm1<<<dim3(256), dim3(256), 0, stream>>>(x, disp, xdT);
  k_zgemm<<<dim3(2048), dim3(256), 0, stream>>>(comb, xdT, z, Se);
  k_reduceS<<<dim3(64), dim3(256), 0, stream>>>(Se, S);
  k_outgemm<<<dim3(2048), dim3(256), 0, stream>>>(z, wT, bias, S, out);
}

// Round 2
// 531.403 us; speedup vs baseline: 1.2065x; 1.2065x over previous
//
#include <hip/hip_runtime.h>

typedef float f32x4 __attribute__((ext_vector_type(4)));
typedef short s16x8 __attribute__((ext_vector_type(8)));
typedef short s16x4 __attribute__((ext_vector_type(4)));

#define DEVI __device__ __forceinline__

static constexpr int B_ = 4, T_ = 4096, D_ = 2048, E_ = 8, C_ = 512, O_ = 2048, I_ = 256;

DEVI short f2bf(float f) {
  unsigned u = __builtin_bit_cast(unsigned, f);
  u += 0x7FFFu + ((u >> 16) & 1u);
  return (short)(u >> 16);
}

// ---------------------------------------------------------------------------
// Kernel 0: w[e][o][i] f32 -> wT[o][e*256+i] bf16
// ---------------------------------------------------------------------------
__global__ __launch_bounds__(256) void k_prep_wT(const float* __restrict__ w,
                                                 short* __restrict__ wT) {
  int idx = blockIdx.x * 256 + threadIdx.x;      // one per 4 elements, [0, 1M)
  int o  = idx >> 9;                             // 512 quads per o-row
  int dd = (idx & 511) << 2;                     // d = e*256+i
  int e = dd >> 8, i = dd & 255;
  f32x4 v = *(const f32x4*)(w + (((size_t)e * O_ + o) * I_ + i));
  s16x4 p;
#pragma unroll
  for (int j = 0; j < 4; j++) p[j] = f2bf(v[j]);
  *(s16x4*)(wT + (size_t)o * D_ + dd) = p;
}

// ---------------------------------------------------------------------------
// Kernel 1 (split-K): xdF[b,e][i][c] += sum_{t in chunk} x[b,t,e*256+i]*disp[b,t,e,c]
// Split T into 4 chunks of 1024 -> grid 1024 blocks (4/CU, ~50% occupancy).
// XCD grouping: the 8 tile-blocks of one (be,kc) group land on one XCD so the
// shared x/disp panels hit L2.
// Tile: 128(i) x 128(c), BK=64(t). f32 atomicAdd epilogue into xdF.
// ---------------------------------------------------------------------------
__global__ __launch_bounds__(256) void k_gemm1(const float* __restrict__ x,
                                               const float* __restrict__ disp,
                                               float* __restrict__ xdF) {
  __shared__ short lX[64 * 128];
  __shared__ short lD[64 * 128];
  const int tid = threadIdx.x;
  const int bid = blockIdx.x;
  // XCD-aware grouping: group g (8 blocks) contiguous on XCD g%8
  const int xcd = bid & 7, slot = bid >> 3;
  const int g  = (slot >> 3) * 8 + xcd;          // 0..127 = 32 be x 4 kc
  const int jj = slot & 7;                       // tile within group
  const int be = g >> 2, kc = g & 3;
  const int mt = jj >> 2, nt = jj & 3;
  const int b = be >> 3, e = be & 7;
  const int lane = tid & 63, wid = tid >> 6;
  const int wm = wid >> 1, wn = wid & 1;
  const int gg = lane >> 4, lr = lane & 15;

  const size_t xbase = (size_t)b * T_ * D_ + (size_t)e * I_ + (size_t)mt * 128;
  const size_t dbase = (size_t)b * T_ * (E_ * C_) + (size_t)e * C_ + (size_t)nt * 128;

  const f32x4 z4 = {0.f, 0.f, 0.f, 0.f};
  f32x4 acc[4][4];
#pragma unroll
  for (int i = 0; i < 4; i++)
#pragma unroll
    for (int j = 0; j < 4; j++) acc[i][j] = z4;

  const int kend = kc * 1024 + 1024;
  for (int kt = kc * 1024; kt < kend; kt += 64) {
    __syncthreads();
#pragma unroll
    for (int cc = 0; cc < 4; cc++) {
      const int q = tid + 256 * cc;
      const int tr = q >> 4;               // 0..63  (t within tile)
      const int i8 = (q & 15) << 3;        // 0..120 (col chunk)
      const int sw = ((tr >> 3) & 3) << 4; // ushort-index XOR, bits 4-5
      const float* sx = x + xbase + (size_t)(kt + tr) * D_ + i8;
      f32x4 a0 = *(const f32x4*)sx;
      f32x4 a1 = *(const f32x4*)(sx + 4);
      s16x8 pa;
#pragma unroll
      for (int j = 0; j < 4; j++) { pa[j] = f2bf(a0[j]); pa[4 + j] = f2bf(a1[j]); }
      *(s16x8*)&lX[tr * 128 + (i8 ^ sw)] = pa;
      const float* sd = disp + dbase + (size_t)(kt + tr) * (E_ * C_) + i8;
      f32x4 d0 = *(const f32x4*)sd;
      f32x4 d1 = *(const f32x4*)(sd + 4);
      s16x8 pd;
#pragma unroll
      for (int j = 0; j < 4; j++) { pd[j] = f2bf(d0[j]); pd[4 + j] = f2bf(d1[j]); }
      *(s16x8*)&lD[tr * 128 + (i8 ^ sw)] = pd;
    }
    __syncthreads();
#pragma unroll
    for (int kk = 0; kk < 2; kk++) {
      const int tb = kk * 32 + gg * 8;       // this lane's k(t) base
      const int sw = ((tb >> 3) & 3) << 4;   // constant over j (tb mult of 8)
      s16x8 af[4], bf[4];
#pragma unroll
      for (int mi = 0; mi < 4; mi++) {
        const int base = tb * 128 + ((wm * 64 + mi * 16 + lr) ^ sw);
        s16x8 a;
#pragma unroll
        for (int j = 0; j < 8; j++) a[j] = lX[base + 128 * j];
        af[mi] = a;
      }
#pragma unroll
      for (int ni = 0; ni < 4; ni++) {
        const int base = tb * 128 + ((wn * 64 + ni * 16 + lr) ^ sw);
        s16x8 bb;
#pragma unroll
        for (int j = 0; j < 8; j++) bb[j] = lD[base + 128 * j];
        bf[ni] = bb;
      }
#pragma unroll
      for (int mi = 0; mi < 4; mi++)
#pragma unroll
        for (int ni = 0; ni < 4; ni++)
          acc[mi][ni] = __builtin_amdgcn_mfma_f32_16x16x32_bf16(af[mi], bf[ni], acc[mi][ni], 0, 0, 0);
    }
  }
  float* op = xdF + (size_t)be * I_ * C_;
#pragma unroll
  for (int mi = 0; mi < 4; mi++)
#pragma unroll
    for (int ni = 0; ni < 4; ni++)
#pragma unroll
      for (int r = 0; r < 4; r++) {
        const int ig = mt * 128 + wm * 64 + mi * 16 + gg * 4 + r;
        const int cg = nt * 128 + wn * 64 + ni * 16 + lr;
        atomicAdd(op + (size_t)ig * C_ + cg, acc[mi][ni][r]);
      }
}

// ---------------------------------------------------------------------------
// Kernel 1b: xdT = bf16(xdF)   (4M elements)
// ---------------------------------------------------------------------------
__global__ __launch_bounds__(256) void k_cvt(const float* __restrict__ xdF,
                                             short* __restrict__ xdT) {
  int idx = blockIdx.x * 256 + threadIdx.x;   // one per 4 elements
  f32x4 v = *(const f32x4*)(xdF + (size_t)idx * 4);
  s16x4 p;
#pragma unroll
  for (int j = 0; j < 4; j++) p[j] = f2bf(v[j]);
  *(s16x4*)(xdT + (size_t)idx * 4) = p;
}

// ---------------------------------------------------------------------------
// Kernel 2: z[b][t][e*256+i] = sum_c comb[b,t,e,c] * xdT[b,e][i][c]  (bf16)
// Also (nt==0 blocks): Se[b,e,t] = sum_c comb[b,t,e,c]  (f32, pre-cvt values)
// Tile 128(t) x 128(i), BK=64(c). Grid: 32 (b,e) x (32 mt x 2 nt) = 2048.
// ---------------------------------------------------------------------------
__global__ __launch_bounds__(256) void k_zgemm(const float* __restrict__ comb,
                                               const short* __restrict__ xdT,
                                               short* __restrict__ z,
                                               float* __restrict__ Se) {
  __shared__ short lA[128 * 64];
  __shared__ short lB[128 * 64];
  const int tid = threadIdx.x;
  const int bid = blockIdx.x;
  const int be = bid >> 6, rest = bid & 63;
  const int mt = rest >> 1, nt = rest & 1;
  const int b = be >> 3, e = be & 7;
  const int lane = tid & 63, wid = tid >> 6;
  const int wm = wid >> 1, wn = wid & 1;
  const int g = lane >> 4, lr = lane & 15;

  const size_t abase = (size_t)b * T_ * (E_ * C_) + (size_t)(mt * 128) * (E_ * C_) + (size_t)e * C_;
  const short* Bsrc = xdT + (size_t)be * I_ * C_ + (size_t)(nt * 128) * C_;

  float rs[4] = {0.f, 0.f, 0.f, 0.f};
  const f32x4 z4 = {0.f, 0.f, 0.f, 0.f};
  f32x4 acc[4][4];
#pragma unroll
  for (int i = 0; i < 4; i++)
#pragma unroll
    for (int j = 0; j < 4; j++) acc[i][j] = z4;

  for (int ct = 0; ct < C_; ct += 64) {
    __syncthreads();
#pragma unroll
    for (int cc = 0; cc < 4; cc++) {
      const int q = tid + 256 * cc;
      const int row = q >> 3;           // 0..127
      const int k8 = (q & 7) << 3;      // 0..56
      const int sw = (row & 7) << 3;    // T2 swizzle (byte<<4 == ushort<<3)
      const float* sa = comb + abase + (size_t)row * (E_ * C_) + ct + k8;
      f32x4 a0 = *(const f32x4*)sa;
      f32x4 a1 = *(const f32x4*)(sa + 4);
      rs[cc] += a0[0] + a0[1] + a0[2] + a0[3] + a1[0] + a1[1] + a1[2] + a1[3];
      s16x8 pa;
#pragma unroll
      for (int j = 0; j < 4; j++) { pa[j] = f2bf(a0[j]); pa[4 + j] = f2bf(a1[j]); }
      *(s16x8*)&lA[row * 64 + (k8 ^ sw)] = pa;
      s16x8 pb = *(const s16x8*)(Bsrc + (size_t)row * C_ + ct + k8);
      *(s16x8*)&lB[row * 64 + (k8 ^ sw)] = pb;
    }
    __syncthreads();
#pragma unroll
    for (int kk = 0; kk < 2; kk++) {
      const int kb = kk * 32 + g * 8;
      s16x8 af[4], bf[4];
#pragma unroll
      for (int mi = 0; mi < 4; mi++) {
        const int r = wm * 64 + mi * 16 + lr;
        af[mi] = *(const s16x8*)&lA[r * 64 + (kb ^ ((r & 7) << 3))];
      }
#pragma unroll
      for (int ni = 0; ni < 4; ni++) {
        const int r = wn * 64 + ni * 16 + lr;
        bf[ni] = *(const s16x8*)&lB[r * 64 + (kb ^ ((r & 7) << 3))];
      }
#pragma unroll
      for (int mi = 0; mi < 4; mi++)
#pragma unroll
        for (int ni = 0; ni < 4; ni++)
          acc[mi][ni] = __builtin_amdgcn_mfma_f32_16x16x32_bf16(af[mi], bf[ni], acc[mi][ni], 0, 0, 0);
    }
  }
  if (nt == 0) {
#pragma unroll
    for (int cc = 0; cc < 4; cc++) {
      float v = rs[cc];
      v += __shfl_xor(v, 1);
      v += __shfl_xor(v, 2);
      v += __shfl_xor(v, 4);
      if ((tid & 7) == 0)
        Se[((size_t)b * E_ + e) * T_ + mt * 128 + (tid >> 3) + 32 * cc] = v;
    }
  }
#pragma unroll
  for (int mi = 0; mi < 4; mi++)
#pragma unroll
    for (int ni = 0; ni < 4; ni++)
#pragma unroll
      for (int r = 0; r < 4; r++) {
        const int tg = mt * 128 + wm * 64 + mi * 16 + g * 4 + r;
        const int ig = nt * 128 + wn * 64 + ni * 16 + lr;
        z[((size_t)b * T_ + tg) * D_ + e * I_ + ig] = f2bf(acc[mi][ni][r]);
      }
}

// ---------------------------------------------------------------------------
// Kernel 3: S[b,t] = sum_e Se[b,e,t]
// ---------------------------------------------------------------------------
__global__ __launch_bounds__(256) void k_reduceS(const float* __restrict__ Se,
                                                 float* __restrict__ S) {
  int idx = blockIdx.x * 256 + threadIdx.x;  // [0, B*T)
  int b = idx >> 12, t = idx & (T_ - 1);
  float s = 0.f;
#pragma unroll
  for (int e = 0; e < E_; e++) s += Se[((size_t)b * E_ + e) * T_ + t];
  S[idx] = s;
}

// ---------------------------------------------------------------------------
// Kernel 4: out[b][t][o] = sum_d z[b][t][d]*wT[o][d] + bias[o]*S[b,t]  (f32)
// Tile 128(t) x 128(o), BK=64(d). Grid: 4 b x (32 mt x 16 nt) = 2048.
// ---------------------------------------------------------------------------
__global__ __launch_bounds__(256) void k_outgemm(const short* __restrict__ z,
                                                 const short* __restrict__ wT,
                                                 const float* __restrict__ bias,
                                                 const float* __restrict__ S,
                                                 float* __restrict__ out) {
  __shared__ short lA[128 * 64];
  __shared__ short lB[128 * 64];
  const int tid = threadIdx.x;
  const int bid = blockIdx.x;
  const int b = bid >> 9, rest = bid & 511;
  const int mt = rest >> 4, nt = rest & 15;
  const int lane = tid & 63, wid = tid >> 6;
  const int wm = wid >> 1, wn = wid & 1;
  const int g = lane >> 4, lr = lane & 15;

  const short* Asrc = z + ((size_t)b * T_ + mt * 128) * D_;
  const short* Bsrc = wT + (size_t)(nt * 128) * D_;

  const f32x4 z4 = {0.f, 0.f, 0.f, 0.f};
  f32x4 acc[4][4];
#pragma unroll
  for (int i = 0; i < 4; i++)
#pragma unroll
    for (int j = 0; j < 4; j++) acc[i][j] = z4;

  for (int dt = 0; dt < D_; dt += 64) {
    __syncthreads();
#pragma unroll
    for (int cc = 0; cc < 4; cc++) {
      const int q = tid + 256 * cc;
      const int row = q >> 3;
      const int k8 = (q & 7) << 3;
      const int sw = (row & 7) << 3;
      s16x8 pa = *(const s16x8*)(Asrc + (size_t)row * D_ + dt + k8);
      *(s16x8*)&lA[row * 64 + (k8 ^ sw)] = pa;
      s16x8 pb = *(const s16x8*)(Bsrc + (size_t)row * D_ + dt + k8);
      *(s16x8*)&lB[row * 64 + (k8 ^ sw)] = pb;
    }
    __syncthreads();
#pragma unroll
    for (int kk = 0; kk < 2; kk++) {
      const int kb = kk * 32 + g * 8;
      s16x8 af[4], bf[4];
#pragma unroll
      for (int mi = 0; mi < 4; mi++) {
        const int r = wm * 64 + mi * 16 + lr;
        af[mi] = *(const s16x8*)&lA[r * 64 + (kb ^ ((r & 7) << 3))];
      }
#pragma unroll
      for (int ni = 0; ni < 4; ni++) {
        const int r = wn * 64 + ni * 16 + lr;
        bf[ni] = *(const s16x8*)&lB[r * 64 + (kb ^ ((r & 7) << 3))];
      }
#pragma unroll
      for (int mi = 0; mi < 4; mi++)
#pragma unroll
        for (int ni = 0; ni < 4; ni++)
          acc[mi][ni] = __builtin_amdgcn_mfma_f32_16x16x32_bf16(af[mi], bf[ni], acc[mi][ni], 0, 0, 0);
    }
  }
  float bia[4];
#pragma unroll
  for (int ni = 0; ni < 4; ni++) bia[ni] = bias[nt * 128 + wn * 64 + ni * 16 + lr];
#pragma unroll
  for (int mi = 0; mi < 4; mi++)
#pragma unroll
    for (int r = 0; r < 4; r++) {
      const int tg = mt * 128 + wm * 64 + mi * 16 + g * 4 + r;
      const float s = S[(size_t)b * T_ + tg];
#pragma unroll
      for (int ni = 0; ni < 4; ni++) {
        const int og = nt * 128 + wn * 64 + ni * 16 + lr;
        out[((size_t)b * T_ + tg) * O_ + og] = acc[mi][ni][r] + bia[ni] * s;
      }
    }
}

// ---------------------------------------------------------------------------
extern "C" void kernel_launch(void* const* d_in, const int* in_sizes, int n_in,
                              void* d_out, int out_size, void* d_ws, size_t ws_size,
                              hipStream_t stream) {
  const float* x    = (const float*)d_in[0];
  const float* comb = (const float*)d_in[1];
  const float* disp = (const float*)d_in[2];
  const float* w    = (const float*)d_in[3];
  const float* bias = (const float*)d_in[4];
  float* out = (float*)d_out;

  char* ws = (char*)d_ws;
  short* wT  = (short*)(ws);                    //  8,388,608 B  [O][D] bf16
  short* xdT = (short*)(ws + 8388608);          //  8,388,608 B  [B,E][I][C] bf16
  short* z   = (short*)(ws + 16777216);         // 67,108,864 B  [B][T][D] bf16
  float* xdF = (float*)(ws + 16777216);         // 16,777,216 B  [B,E][I][C] f32 (aliases z; dead before zgemm writes z)
  float* Se  = (float*)(ws + 83886080);         //    524,288 B  [B][E][T] f32
  float* S   = (float*)(ws + 84410368);         //     65,536 B  [B][T] f32

  hipMemsetAsync(xdF, 0, 16777216, stream);
  k_prep_wT<<<dim3(4096), dim3(256), 0, stream>>>(w, wT);
  k_gemm1<<<dim3(1024), dim3(256), 0, stream>>>(x, disp, xdF);
  k_cvt<<<dim3(4096), dim3(256), 0, stream>>>(xdF, xdT);
  k_zgemm<<<dim3(2048), dim3(256), 0, stream>>>(comb, xdT, z, Se);
  k_reduceS<<<dim3(64), dim3(256), 0, stream>>>(Se, S);
  k_outgemm<<<dim3(2048), dim3(256), 0, stream>>>(z, wT, bias, S, out);
}

// Round 3
// 454.987 us; speedup vs baseline: 1.4092x; 1.1680x over previous
//
#include <hip/hip_runtime.h>

typedef float f32x4 __attribute__((ext_vector_type(4)));
typedef short s16x8 __attribute__((ext_vector_type(8)));
typedef short s16x4 __attribute__((ext_vector_type(4)));

#define DEVI __device__ __forceinline__

static constexpr int B_ = 4, T_ = 4096, D_ = 2048, E_ = 8, C_ = 512, O_ = 2048, I_ = 256;

DEVI short f2bf(float f) {
  unsigned u = __builtin_bit_cast(unsigned, f);
  u += 0x7FFFu + ((u >> 16) & 1u);
  return (short)(u >> 16);
}

DEVI void gll16(const short* gsrc, short* ldst) {
  __builtin_amdgcn_global_load_lds(
      (const __attribute__((address_space(1))) void*)gsrc,
      (__attribute__((address_space(3))) void*)ldst, 16, 0, 0);
}

// ---------------------------------------------------------------------------
// Kernel 0: w[e][o][i] f32 -> wT[o][e*256+i] bf16, PRE-SWIZZLED:
// d-8-block XORed by (o&7) so outgemm can global_load_lds linearly.
// ---------------------------------------------------------------------------
__global__ __launch_bounds__(256) void k_prep_wT(const float* __restrict__ w,
                                                 short* __restrict__ wT) {
  int idx = blockIdx.x * 256 + threadIdx.x;      // one per 4 elements, [0, 1M)
  int o  = idx >> 9;                             // 512 quads per o-row
  int dd = (idx & 511) << 2;                     // d = e*256+i
  int e = dd >> 8, i = dd & 255;
  f32x4 v = *(const f32x4*)(w + (((size_t)e * O_ + o) * I_ + i));
  s16x4 p;
#pragma unroll
  for (int j = 0; j < 4; j++) p[j] = f2bf(v[j]);
  int dsw = (dd & ~63) | (dd & 7) | ((((dd >> 3) & 7) ^ (o & 7)) << 3);
  *(s16x4*)(wT + (size_t)o * D_ + dsw) = p;
}

// ---------------------------------------------------------------------------
// Kernel 1 (split-K): xdF[b,e][i][c] += sum_{t in chunk} x[b,t,e*256+i]*disp[b,t,e,c]
// Transposed LDS staging: pair-packed ds_write_b32 into [i][t]/[c][t] tiles with
// XOR swizzle S(i)=(((i&7)^((i>>3)&7))<<3); fragments via ds_read_b128.
// Tile: 128(i) x 128(c), BK=64(t), split-K=4. Grid 1024, XCD-grouped.
// ---------------------------------------------------------------------------
__global__ __launch_bounds__(256) void k_gemm1(const float* __restrict__ x,
                                               const float* __restrict__ disp,
                                               float* __restrict__ xdF) {
  __shared__ short lXT[128 * 64];  // [i][t] swizzled
  __shared__ short lDT[128 * 64];  // [c][t] swizzled
  const int tid = threadIdx.x;
  const int bid = blockIdx.x;
  const int xcd = bid & 7, slot = bid >> 3;
  const int grp = (slot >> 3) * 8 + xcd;         // 0..127 = 32 be x 4 kc
  const int jj = slot & 7;                       // tile within group
  const int be = grp >> 2, kc = grp & 3;
  const int mt = jj >> 2, nt = jj & 3;
  const int b = be >> 3, e = be & 7;
  const int lane = tid & 63, wid = tid >> 6;
  const int wm = wid >> 1, wn = wid & 1;
  const int g = lane >> 4, lr = lane & 15;

  const size_t xbase = (size_t)b * T_ * D_ + (size_t)e * I_ + (size_t)mt * 128;
  const size_t dbase = (size_t)b * T_ * (E_ * C_) + (size_t)e * C_ + (size_t)nt * 128;

  const f32x4 z4 = {0.f, 0.f, 0.f, 0.f};
  f32x4 acc[4][4];
#pragma unroll
  for (int i = 0; i < 4; i++)
#pragma unroll
    for (int j = 0; j < 4; j++) acc[i][j] = z4;

  const int kend = kc * 1024 + 1024;
  for (int kt = kc * 1024; kt < kend; kt += 64) {
    __syncthreads();
#pragma unroll
    for (int cc = 0; cc < 2; cc++) {
      const int q  = tid + 256 * cc;       // 0..511
      const int t0 = (q >> 4) * 2;         // 0..62 even
      const int i8 = (q & 15) * 8;
      const float* sx = x + xbase + (size_t)(kt + t0) * D_ + i8;
      f32x4 xa0 = *(const f32x4*)sx;
      f32x4 xa1 = *(const f32x4*)(sx + 4);
      f32x4 xb0 = *(const f32x4*)(sx + D_);
      f32x4 xb1 = *(const f32x4*)(sx + D_ + 4);
      const float* sd = disp + dbase + (size_t)(kt + t0) * (E_ * C_) + i8;
      f32x4 da0 = *(const f32x4*)sd;
      f32x4 da1 = *(const f32x4*)(sd + 4);
      f32x4 db0 = *(const f32x4*)(sd + E_ * C_);
      f32x4 db1 = *(const f32x4*)(sd + E_ * C_ + 4);
#pragma unroll
      for (int j = 0; j < 8; j++) {
        const int i = i8 + j;
        const int sws = ((j ^ ((i >> 3) & 7)) << 3);
        const int ad = i * 64 + (t0 ^ sws);
        float va = (j < 4) ? xa0[j] : xa1[j - 4];
        float vb = (j < 4) ? xb0[j] : xb1[j - 4];
        unsigned px = (unsigned)(unsigned short)f2bf(va) |
                      ((unsigned)(unsigned short)f2bf(vb) << 16);
        *(unsigned*)&lXT[ad] = px;
        float ua = (j < 4) ? da0[j] : da1[j - 4];
        float ub = (j < 4) ? db0[j] : db1[j - 4];
        unsigned pd = (unsigned)(unsigned short)f2bf(ua) |
                      ((unsigned)(unsigned short)f2bf(ub) << 16);
        *(unsigned*)&lDT[ad] = pd;
      }
    }
    __syncthreads();
#pragma unroll
    for (int kk = 0; kk < 2; kk++) {
      const int tb = kk * 32 + g * 8;
      s16x8 af[4], bfr[4];
#pragma unroll
      for (int mi = 0; mi < 4; mi++) {
        const int r = wm * 64 + mi * 16 + lr;
        const int sws = (((r & 7) ^ ((r >> 3) & 7)) << 3);
        af[mi] = *(const s16x8*)&lXT[r * 64 + (tb ^ sws)];
      }
#pragma unroll
      for (int ni = 0; ni < 4; ni++) {
        const int r = wn * 64 + ni * 16 + lr;
        const int sws = (((r & 7) ^ ((r >> 3) & 7)) << 3);
        bfr[ni] = *(const s16x8*)&lDT[r * 64 + (tb ^ sws)];
      }
#pragma unroll
      for (int mi = 0; mi < 4; mi++)
#pragma unroll
        for (int ni = 0; ni < 4; ni++)
          acc[mi][ni] = __builtin_amdgcn_mfma_f32_16x16x32_bf16(af[mi], bfr[ni], acc[mi][ni], 0, 0, 0);
    }
  }
  float* op = xdF + (size_t)be * I_ * C_;
#pragma unroll
  for (int mi = 0; mi < 4; mi++)
#pragma unroll
    for (int ni = 0; ni < 4; ni++)
#pragma unroll
      for (int r = 0; r < 4; r++) {
        const int ig = mt * 128 + wm * 64 + mi * 16 + g * 4 + r;
        const int cg = nt * 128 + wn * 64 + ni * 16 + lr;
        atomicAdd(op + (size_t)ig * C_ + cg, acc[mi][ni][r]);
      }
}

// ---------------------------------------------------------------------------
// Kernel 1b: xdT = bf16(xdF)   (4M elements)
// ---------------------------------------------------------------------------
__global__ __launch_bounds__(256) void k_cvt(const float* __restrict__ xdF,
                                             short* __restrict__ xdT) {
  int idx = blockIdx.x * 256 + threadIdx.x;   // one per 4 elements
  f32x4 v = *(const f32x4*)(xdF + (size_t)idx * 4);
  s16x4 p;
#pragma unroll
  for (int j = 0; j < 4; j++) p[j] = f2bf(v[j]);
  *(s16x4*)(xdT + (size_t)idx * 4) = p;
}

// ---------------------------------------------------------------------------
// Kernel 2: z[b][t][d'] = sum_c comb[b,t,e,c] * xdT[b,e][i][c]  (bf16)
// z written PRE-SWIZZLED (d-8-block ^ (t&7)) for outgemm's global_load_lds.
// Also (nt==0 blocks): Se[b,e,t] = sum_c comb[b,t,e,c]  (f32, pre-cvt values)
// Tile 128(t) x 128(i), BK=64(c). Grid: 32 (b,e) x (32 mt x 2 nt) = 2048.
// ---------------------------------------------------------------------------
__global__ __launch_bounds__(256) void k_zgemm(const float* __restrict__ comb,
                                               const short* __restrict__ xdT,
                                               short* __restrict__ z,
                                               float* __restrict__ Se) {
  __shared__ short lA[128 * 64];
  __shared__ short lB[128 * 64];
  const int tid = threadIdx.x;
  const int bid = blockIdx.x;
  const int be = bid >> 6, rest = bid & 63;
  const int mt = rest >> 1, nt = rest & 1;
  const int b = be >> 3, e = be & 7;
  const int lane = tid & 63, wid = tid >> 6;
  const int wm = wid >> 1, wn = wid & 1;
  const int g = lane >> 4, lr = lane & 15;

  const size_t abase = (size_t)b * T_ * (E_ * C_) + (size_t)(mt * 128) * (E_ * C_) + (size_t)e * C_;
  const short* Bsrc = xdT + (size_t)be * I_ * C_ + (size_t)(nt * 128) * C_;

  float rs[4] = {0.f, 0.f, 0.f, 0.f};
  const f32x4 z4 = {0.f, 0.f, 0.f, 0.f};
  f32x4 acc[4][4];
#pragma unroll
  for (int i = 0; i < 4; i++)
#pragma unroll
    for (int j = 0; j < 4; j++) acc[i][j] = z4;

  for (int ct = 0; ct < C_; ct += 64) {
    __syncthreads();
#pragma unroll
    for (int cc = 0; cc < 4; cc++) {
      const int q = tid + 256 * cc;
      const int row = q >> 3;           // 0..127
      const int k8 = (q & 7) << 3;      // 0..56
      const int sw = (row & 7) << 3;    // T2 swizzle (byte<<4 == ushort<<3)
      const float* sa = comb + abase + (size_t)row * (E_ * C_) + ct + k8;
      f32x4 a0 = *(const f32x4*)sa;
      f32x4 a1 = *(const f32x4*)(sa + 4);
      rs[cc] += a0[0] + a0[1] + a0[2] + a0[3] + a1[0] + a1[1] + a1[2] + a1[3];
      s16x8 pa;
#pragma unroll
      for (int j = 0; j < 4; j++) { pa[j] = f2bf(a0[j]); pa[4 + j] = f2bf(a1[j]); }
      *(s16x8*)&lA[row * 64 + (k8 ^ sw)] = pa;
      s16x8 pb = *(const s16x8*)(Bsrc + (size_t)row * C_ + ct + k8);
      *(s16x8*)&lB[row * 64 + (k8 ^ sw)] = pb;
    }
    __syncthreads();
#pragma unroll
    for (int kk = 0; kk < 2; kk++) {
      const int kb = kk * 32 + g * 8;
      s16x8 af[4], bf[4];
#pragma unroll
      for (int mi = 0; mi < 4; mi++) {
        const int r = wm * 64 + mi * 16 + lr;
        af[mi] = *(const s16x8*)&lA[r * 64 + (kb ^ ((r & 7) << 3))];
      }
#pragma unroll
      for (int ni = 0; ni < 4; ni++) {
        const int r = wn * 64 + ni * 16 + lr;
        bf[ni] = *(const s16x8*)&lB[r * 64 + (kb ^ ((r & 7) << 3))];
      }
#pragma unroll
      for (int mi = 0; mi < 4; mi++)
#pragma unroll
        for (int ni = 0; ni < 4; ni++)
          acc[mi][ni] = __builtin_amdgcn_mfma_f32_16x16x32_bf16(af[mi], bf[ni], acc[mi][ni], 0, 0, 0);
    }
  }
  if (nt == 0) {
#pragma unroll
    for (int cc = 0; cc < 4; cc++) {
      float v = rs[cc];
      v += __shfl_xor(v, 1);
      v += __shfl_xor(v, 2);
      v += __shfl_xor(v, 4);
      if ((tid & 7) == 0)
        Se[((size_t)b * E_ + e) * T_ + mt * 128 + (tid >> 3) + 32 * cc] = v;
    }
  }
#pragma unroll
  for (int mi = 0; mi < 4; mi++)
#pragma unroll
    for (int ni = 0; ni < 4; ni++)
#pragma unroll
      for (int r = 0; r < 4; r++) {
        const int tg = mt * 128 + wm * 64 + mi * 16 + g * 4 + r;
        const int ig = nt * 128 + wn * 64 + ni * 16 + lr;
        const int d = e * I_ + ig;
        const int dsw = (d & ~63) | (d & 7) | ((((d >> 3) & 7) ^ (tg & 7)) << 3);
        z[((size_t)b * T_ + tg) * D_ + dsw] = f2bf(acc[mi][ni][r]);
      }
}

// ---------------------------------------------------------------------------
// Kernel 3: S[b,t] = sum_e Se[b,e,t]
// ---------------------------------------------------------------------------
__global__ __launch_bounds__(256) void k_reduceS(const float* __restrict__ Se,
                                                 float* __restrict__ S) {
  int idx = blockIdx.x * 256 + threadIdx.x;  // [0, B*T)
  int b = idx >> 12, t = idx & (T_ - 1);
  float s = 0.f;
#pragma unroll
  for (int e = 0; e < E_; e++) s += Se[((size_t)b * E_ + e) * T_ + t];
  S[idx] = s;
}

// ---------------------------------------------------------------------------
// Kernel 4: out[b][t][o] = sum_d z[b][t][d]*wT[o][d] + bias[o]*S[b,t]  (f32)
// z/wT are pre-swizzled in global -> linear global_load_lds staging, XOR on read.
// Tile 128(t) x 128(o), BK=64(d). Grid 2048, XCD-grouped by (b,mt).
// ---------------------------------------------------------------------------
__global__ __launch_bounds__(256) void k_outgemm(const short* __restrict__ z,
                                                 const short* __restrict__ wT,
                                                 const float* __restrict__ bias,
                                                 const float* __restrict__ S,
                                                 float* __restrict__ out) {
  __shared__ short lA[128 * 64];
  __shared__ short lB[128 * 64];
  const int tid = threadIdx.x;
  const int bid = blockIdx.x;
  // XCD grouping: 16 nt-blocks of one (b,mt) group on one XCD (share z panel)
  const int xcd = bid & 7, slot = bid >> 3;
  const int grp = (slot >> 4) * 8 + xcd;   // 0..127 = b*32+mt
  const int nt = slot & 15;
  const int b = grp >> 5, mt = grp & 31;
  const int lane = tid & 63, wid = tid >> 6;
  const int wm = wid >> 1, wn = wid & 1;
  const int g = lane >> 4, lr = lane & 15;

  const short* Asrc = z + ((size_t)b * T_ + mt * 128) * D_;
  const short* Bsrc = wT + (size_t)(nt * 128) * D_;

  const f32x4 z4 = {0.f, 0.f, 0.f, 0.f};
  f32x4 acc[4][4];
#pragma unroll
  for (int i = 0; i < 4; i++)
#pragma unroll
    for (int j = 0; j < 4; j++) acc[i][j] = z4;

  const int row0 = wid * 32;           // this wave's 32-row stripe
  const int rsub = lane >> 3;          // row within 8-row chunk
  const int k8 = (lane & 7) * 8;       // 8-short column chunk

  for (int dt = 0; dt < D_; dt += 64) {
    __syncthreads();
#pragma unroll
    for (int it = 0; it < 4; it++) {
      const int rr = row0 + it * 8 + rsub;
      gll16(Asrc + (size_t)rr * D_ + dt + k8, &lA[(row0 + it * 8) * 64]);
      gll16(Bsrc + (size_t)rr * D_ + dt + k8, &lB[(row0 + it * 8) * 64]);
    }
    __syncthreads();
#pragma unroll
    for (int kk = 0; kk < 2; kk++) {
      const int kb = kk * 32 + g * 8;
      s16x8 af[4], bf[4];
#pragma unroll
      for (int mi = 0; mi < 4; mi++) {
        const int r = wm * 64 + mi * 16 + lr;
        af[mi] = *(const s16x8*)&lA[r * 64 + (kb ^ ((r & 7) << 3))];
      }
#pragma unroll
      for (int ni = 0; ni < 4; ni++) {
        const int r = wn * 64 + ni * 16 + lr;
        bf[ni] = *(const s16x8*)&lB[r * 64 + (kb ^ ((r & 7) << 3))];
      }
#pragma unroll
      for (int mi = 0; mi < 4; mi++)
#pragma unroll
        for (int ni = 0; ni < 4; ni++)
          acc[mi][ni] = __builtin_amdgcn_mfma_f32_16x16x32_bf16(af[mi], bf[ni], acc[mi][ni], 0, 0, 0);
    }
  }
  float bia[4];
#pragma unroll
  for (int ni = 0; ni < 4; ni++) bia[ni] = bias[nt * 128 + wn * 64 + ni * 16 + lr];
#pragma unroll
  for (int mi = 0; mi < 4; mi++)
#pragma unroll
    for (int r = 0; r < 4; r++) {
      const int tg = mt * 128 + wm * 64 + mi * 16 + g * 4 + r;
      const float s = S[(size_t)b * T_ + tg];
#pragma unroll
      for (int ni = 0; ni < 4; ni++) {
        const int og = nt * 128 + wn * 64 + ni * 16 + lr;
        out[((size_t)b * T_ + tg) * O_ + og] = acc[mi][ni][r] + bia[ni] * s;
      }
    }
}

// ---------------------------------------------------------------------------
extern "C" void kernel_launch(void* const* d_in, const int* in_sizes, int n_in,
                              void* d_out, int out_size, void* d_ws, size_t ws_size,
                              hipStream_t stream) {
  const float* x    = (const float*)d_in[0];
  const float* comb = (const float*)d_in[1];
  const float* disp = (const float*)d_in[2];
  const float* w    = (const float*)d_in[3];
  const float* bias = (const float*)d_in[4];
  float* out = (float*)d_out;

  char* ws = (char*)d_ws;
  short* wT  = (short*)(ws);                    //  8,388,608 B  [O][D] bf16 (pre-swizzled)
  short* xdT = (short*)(ws + 8388608);          //  8,388,608 B  [B,E][I][C] bf16
  short* z   = (short*)(ws + 16777216);         // 67,108,864 B  [B][T][D] bf16 (pre-swizzled)
  float* xdF = (float*)(ws + 16777216);         // 16,777,216 B  [B,E][I][C] f32 (aliases z; dead before zgemm writes z)
  float* Se  = (float*)(ws + 83886080);         //    524,288 B  [B][E][T] f32
  float* S   = (float*)(ws + 84410368);         //     65,536 B  [B][T] f32

  hipMemsetAsync(xdF, 0, 16777216, stream);
  k_prep_wT<<<dim3(4096), dim3(256), 0, stream>>>(w, wT);
  k_gemm1<<<dim3(1024), dim3(256), 0, stream>>>(x, disp, xdF);
  k_cvt<<<dim3(4096), dim3(256), 0, stream>>>(xdF, xdT);
  k_zgemm<<<dim3(2048), dim3(256), 0, stream>>>(comb, xdT, z, Se);
  k_reduceS<<<dim3(64), dim3(256), 0, stream>>>(Se, S);
  k_outgemm<<<dim3(2048), dim3(256), 0, stream>>>(z, wT, bias, S, out);
}

// Round 5
// 415.285 us; speedup vs baseline: 1.5439x; 1.0956x over previous
//
#include <hip/hip_runtime.h>

typedef float f32x4 __attribute__((ext_vector_type(4)));
typedef short s16x8 __attribute__((ext_vector_type(8)));
typedef short s16x4 __attribute__((ext_vector_type(4)));

#define DEVI __device__ __forceinline__

static constexpr int B_ = 4, T_ = 4096, D_ = 2048, E_ = 8, C_ = 512, O_ = 2048, I_ = 256;

DEVI short f2bf(float f) {
  unsigned u = __builtin_bit_cast(unsigned, f);
  u += 0x7FFFu + ((u >> 16) & 1u);
  return (short)(u >> 16);
}

DEVI void gll16(const short* gsrc, short* ldst) {
  __builtin_amdgcn_global_load_lds(
      (const __attribute__((address_space(1))) void*)gsrc,
      (__attribute__((address_space(3))) void*)ldst, 16, 0, 0);
}

// ---------------------------------------------------------------------------
// Kernel 0: w[e][o][i] f32 -> wT[o][e*256+i] bf16, PRE-SWIZZLED:
// d-8-block XORed by (o&7) so outgemm can global_load_lds linearly.
// ---------------------------------------------------------------------------
__global__ __launch_bounds__(256) void k_prep_wT(const float* __restrict__ w,
                                                 short* __restrict__ wT) {
  int idx = blockIdx.x * 256 + threadIdx.x;      // one per 4 elements, [0, 1M)
  int o  = idx >> 9;                             // 512 quads per o-row
  int dd = (idx & 511) << 2;                     // d = e*256+i
  int e = dd >> 8, i = dd & 255;
  f32x4 v = *(const f32x4*)(w + (((size_t)e * O_ + o) * I_ + i));
  s16x4 p;
#pragma unroll
  for (int j = 0; j < 4; j++) p[j] = f2bf(v[j]);
  int dsw = (dd & ~63) | (dd & 7) | ((((dd >> 3) & 7) ^ (o & 7)) << 3);
  *(s16x4*)(wT + (size_t)o * D_ + dsw) = p;
}

// ---------------------------------------------------------------------------
// Kernel 1 (split-K): xdF[b,e][i][c] += sum_{t in chunk} x[b,t,e*256+i]*disp[b,t,e,c]
// Transposed LDS staging: pair-packed ds_write_b32 into [i][t]/[c][t] tiles with
// XOR swizzle; fragments via ds_read_b128. Tile 128x128, BK=64, split-K=4.
// ---------------------------------------------------------------------------
__global__ __launch_bounds__(256) void k_gemm1(const float* __restrict__ x,
                                               const float* __restrict__ disp,
                                               float* __restrict__ xdF) {
  __shared__ short lXT[128 * 64];  // [i][t] swizzled
  __shared__ short lDT[128 * 64];  // [c][t] swizzled
  const int tid = threadIdx.x;
  const int bid = blockIdx.x;
  const int xcd = bid & 7, slot = bid >> 3;
  const int grp = (slot >> 3) * 8 + xcd;         // 0..127 = 32 be x 4 kc
  const int jj = slot & 7;                       // tile within group
  const int be = grp >> 2, kc = grp & 3;
  const int mt = jj >> 2, nt = jj & 3;
  const int b = be >> 3, e = be & 7;
  const int lane = tid & 63, wid = tid >> 6;
  const int wm = wid >> 1, wn = wid & 1;
  const int g = lane >> 4, lr = lane & 15;

  const size_t xbase = (size_t)b * T_ * D_ + (size_t)e * I_ + (size_t)mt * 128;
  const size_t dbase = (size_t)b * T_ * (E_ * C_) + (size_t)e * C_ + (size_t)nt * 128;

  const f32x4 z4 = {0.f, 0.f, 0.f, 0.f};
  f32x4 acc[4][4];
#pragma unroll
  for (int i = 0; i < 4; i++)
#pragma unroll
    for (int j = 0; j < 4; j++) acc[i][j] = z4;

  const int kend = kc * 1024 + 1024;
  for (int kt = kc * 1024; kt < kend; kt += 64) {
    __syncthreads();
#pragma unroll
    for (int cc = 0; cc < 2; cc++) {
      const int q  = tid + 256 * cc;       // 0..511
      const int t0 = (q >> 4) * 2;         // 0..62 even
      const int i8 = (q & 15) * 8;
      const float* sx = x + xbase + (size_t)(kt + t0) * D_ + i8;
      f32x4 xa0 = *(const f32x4*)sx;
      f32x4 xa1 = *(const f32x4*)(sx + 4);
      f32x4 xb0 = *(const f32x4*)(sx + D_);
      f32x4 xb1 = *(const f32x4*)(sx + D_ + 4);
      const float* sd = disp + dbase + (size_t)(kt + t0) * (E_ * C_) + i8;
      f32x4 da0 = *(const f32x4*)sd;
      f32x4 da1 = *(const f32x4*)(sd + 4);
      f32x4 db0 = *(const f32x4*)(sd + E_ * C_);
      f32x4 db1 = *(const f32x4*)(sd + E_ * C_ + 4);
#pragma unroll
      for (int j = 0; j < 8; j++) {
        const int i = i8 + j;
        const int sws = ((j ^ ((i >> 3) & 7)) << 3);
        const int ad = i * 64 + (t0 ^ sws);
        float va = (j < 4) ? xa0[j] : xa1[j - 4];
        float vb = (j < 4) ? xb0[j] : xb1[j - 4];
        unsigned px = (unsigned)(unsigned short)f2bf(va) |
                      ((unsigned)(unsigned short)f2bf(vb) << 16);
        *(unsigned*)&lXT[ad] = px;
        float ua = (j < 4) ? da0[j] : da1[j - 4];
        float ub = (j < 4) ? db0[j] : db1[j - 4];
        unsigned pd = (unsigned)(unsigned short)f2bf(ua) |
                      ((unsigned)(unsigned short)f2bf(ub) << 16);
        *(unsigned*)&lDT[ad] = pd;
      }
    }
    __syncthreads();
#pragma unroll
    for (int kk = 0; kk < 2; kk++) {
      const int tb = kk * 32 + g * 8;
      s16x8 af[4], bfr[4];
#pragma unroll
      for (int mi = 0; mi < 4; mi++) {
        const int r = wm * 64 + mi * 16 + lr;
        const int sws = (((r & 7) ^ ((r >> 3) & 7)) << 3);
        af[mi] = *(const s16x8*)&lXT[r * 64 + (tb ^ sws)];
      }
#pragma unroll
      for (int ni = 0; ni < 4; ni++) {
        const int r = wn * 64 + ni * 16 + lr;
        const int sws = (((r & 7) ^ ((r >> 3) & 7)) << 3);
        bfr[ni] = *(const s16x8*)&lDT[r * 64 + (tb ^ sws)];
      }
#pragma unroll
      for (int mi = 0; mi < 4; mi++)
#pragma unroll
        for (int ni = 0; ni < 4; ni++)
          acc[mi][ni] = __builtin_amdgcn_mfma_f32_16x16x32_bf16(af[mi], bfr[ni], acc[mi][ni], 0, 0, 0);
    }
  }
  float* op = xdF + (size_t)be * I_ * C_;
#pragma unroll
  for (int mi = 0; mi < 4; mi++)
#pragma unroll
    for (int ni = 0; ni < 4; ni++)
#pragma unroll
      for (int r = 0; r < 4; r++) {
        const int ig = mt * 128 + wm * 64 + mi * 16 + g * 4 + r;
        const int cg = nt * 128 + wn * 64 + ni * 16 + lr;
        atomicAdd(op + (size_t)ig * C_ + cg, acc[mi][ni][r]);
      }
}

// ---------------------------------------------------------------------------
// Kernel 1b: xdT = bf16(xdF)   (4M elements)
// ---------------------------------------------------------------------------
__global__ __launch_bounds__(256) void k_cvt(const float* __restrict__ xdF,
                                             short* __restrict__ xdT) {
  int idx = blockIdx.x * 256 + threadIdx.x;   // one per 4 elements
  f32x4 v = *(const f32x4*)(xdF + (size_t)idx * 4);
  s16x4 p;
#pragma unroll
  for (int j = 0; j < 4; j++) p[j] = f2bf(v[j]);
  *(s16x4*)(xdT + (size_t)idx * 4) = p;
}

// ---------------------------------------------------------------------------
// Kernel 2: z[b][t][d'] = sum_c comb[b,t,e,c] * xdT[b,e][i][c]  (bf16)
// z written PRE-SWIZZLED (d-8-block ^ (t&7)) for outgemm's global_load_lds.
// Also (nt==0 blocks): Se[b,e,t] = sum_c comb[b,t,e,c]
// ---------------------------------------------------------------------------
__global__ __launch_bounds__(256) void k_zgemm(const float* __restrict__ comb,
                                               const short* __restrict__ xdT,
                                               short* __restrict__ z,
                                               float* __restrict__ Se) {
  __shared__ short lA[128 * 64];
  __shared__ short lB[128 * 64];
  const int tid = threadIdx.x;
  const int bid = blockIdx.x;
  const int be = bid >> 6, rest = bid & 63;
  const int mt = rest >> 1, nt = rest & 1;
  const int b = be >> 3, e = be & 7;
  const int lane = tid & 63, wid = tid >> 6;
  const int wm = wid >> 1, wn = wid & 1;
  const int g = lane >> 4, lr = lane & 15;

  const size_t abase = (size_t)b * T_ * (E_ * C_) + (size_t)(mt * 128) * (E_ * C_) + (size_t)e * C_;
  const short* Bsrc = xdT + (size_t)be * I_ * C_ + (size_t)(nt * 128) * C_;

  float rs[4] = {0.f, 0.f, 0.f, 0.f};
  const f32x4 z4 = {0.f, 0.f, 0.f, 0.f};
  f32x4 acc[4][4];
#pragma unroll
  for (int i = 0; i < 4; i++)
#pragma unroll
    for (int j = 0; j < 4; j++) acc[i][j] = z4;

  for (int ct = 0; ct < C_; ct += 64) {
    __syncthreads();
#pragma unroll
    for (int cc = 0; cc < 4; cc++) {
      const int q = tid + 256 * cc;
      const int row = q >> 3;           // 0..127
      const int k8 = (q & 7) << 3;      // 0..56
      const int sw = (row & 7) << 3;
      const float* sa = comb + abase + (size_t)row * (E_ * C_) + ct + k8;
      f32x4 a0 = *(const f32x4*)sa;
      f32x4 a1 = *(const f32x4*)(sa + 4);
      rs[cc] += a0[0] + a0[1] + a0[2] + a0[3] + a1[0] + a1[1] + a1[2] + a1[3];
      s16x8 pa;
#pragma unroll
      for (int j = 0; j < 4; j++) { pa[j] = f2bf(a0[j]); pa[4 + j] = f2bf(a1[j]); }
      *(s16x8*)&lA[row * 64 + (k8 ^ sw)] = pa;
      s16x8 pb = *(const s16x8*)(Bsrc + (size_t)row * C_ + ct + k8);
      *(s16x8*)&lB[row * 64 + (k8 ^ sw)] = pb;
    }
    __syncthreads();
#pragma unroll
    for (int kk = 0; kk < 2; kk++) {
      const int kb = kk * 32 + g * 8;
      s16x8 af[4], bf[4];
#pragma unroll
      for (int mi = 0; mi < 4; mi++) {
        const int r = wm * 64 + mi * 16 + lr;
        af[mi] = *(const s16x8*)&lA[r * 64 + (kb ^ ((r & 7) << 3))];
      }
#pragma unroll
      for (int ni = 0; ni < 4; ni++) {
        const int r = wn * 64 + ni * 16 + lr;
        bf[ni] = *(const s16x8*)&lB[r * 64 + (kb ^ ((r & 7) << 3))];
      }
#pragma unroll
      for (int mi = 0; mi < 4; mi++)
#pragma unroll
        for (int ni = 0; ni < 4; ni++)
          acc[mi][ni] = __builtin_amdgcn_mfma_f32_16x16x32_bf16(af[mi], bf[ni], acc[mi][ni], 0, 0, 0);
    }
  }
  if (nt == 0) {
#pragma unroll
    for (int cc = 0; cc < 4; cc++) {
      float v = rs[cc];
      v += __shfl_xor(v, 1);
      v += __shfl_xor(v, 2);
      v += __shfl_xor(v, 4);
      if ((tid & 7) == 0)
        Se[((size_t)b * E_ + e) * T_ + mt * 128 + (tid >> 3) + 32 * cc] = v;
    }
  }
#pragma unroll
  for (int mi = 0; mi < 4; mi++)
#pragma unroll
    for (int ni = 0; ni < 4; ni++)
#pragma unroll
      for (int r = 0; r < 4; r++) {
        const int tg = mt * 128 + wm * 64 + mi * 16 + g * 4 + r;
        const int ig = nt * 128 + wn * 64 + ni * 16 + lr;
        const int d = e * I_ + ig;
        const int dsw = (d & ~63) | (d & 7) | ((((d >> 3) & 7) ^ (tg & 7)) << 3);
        z[((size_t)b * T_ + tg) * D_ + dsw] = f2bf(acc[mi][ni][r]);
      }
}

// ---------------------------------------------------------------------------
// Kernel 3: S[b,t] = sum_e Se[b,e,t]
// ---------------------------------------------------------------------------
__global__ __launch_bounds__(256) void k_reduceS(const float* __restrict__ Se,
                                                 float* __restrict__ S) {
  int idx = blockIdx.x * 256 + threadIdx.x;  // [0, B*T)
  int b = idx >> 12, t = idx & (T_ - 1);
  float s = 0.f;
#pragma unroll
  for (int e = 0; e < E_; e++) s += Se[((size_t)b * E_ + e) * T_ + t];
  S[idx] = s;
}

// ---------------------------------------------------------------------------
// Kernel 4: out[row][o] = sum_d z[row][d]*wT[o][d] + bias[o]*S[row]  (f32)
// 256x256 tile, BK=64, 8 waves (2Mx4N), 128KiB dbuf LDS, 4-phase counted-vmcnt
// schedule (T3+T4), setprio (T5). mh/nh select GLOBAL halves (match staging!).
// Per-wave out: rows {mh*128+wm*64+[0,64)} x cols {nh*128+wn*32+[0,32)}.
// ---------------------------------------------------------------------------
__global__ __launch_bounds__(512, 2) void k_outgemm(const short* __restrict__ z,
                                                    const short* __restrict__ wT,
                                                    const float* __restrict__ bias,
                                                    const float* __restrict__ S,
                                                    float* __restrict__ out) {
  __shared__ short lA[2][256 * 64];
  __shared__ short lB[2][256 * 64];
  const int tid = threadIdx.x;
  const int lane = tid & 63, wid = tid >> 6;   // 8 waves
  const int wm = wid >> 2, wn = wid & 3;       // 2 x 4
  const int g = lane >> 4, lr = lane & 15;

  // XCD chunking: XCD x gets 8 consecutive mt x all 8 nt (nt inner)
  const int bid = blockIdx.x;
  const int swz = (bid & 7) * 64 + (bid >> 3);
  const int mt = swz >> 3, nt = swz & 7;
  const int row0 = mt * 256;                   // token rows (B*T flat)
  const int col0 = nt * 256;                   // O cols

  // staging: wave wid covers rows [h*128 + wid*16, +16) of each half, 2 gll
  const int srow = (wid << 4) + (lane >> 3);   // + issue*8
  const int scol = (lane & 7) << 3;            // shorts
  const short* Abase = z + (size_t)(row0 + srow) * D_ + scol;
  const short* Bbase = wT + (size_t)(col0 + srow) * D_ + scol;

  const f32x4 zero4 = {0.f, 0.f, 0.f, 0.f};
  f32x4 acc[8][4];
#pragma unroll
  for (int i = 0; i < 8; i++)
#pragma unroll
    for (int j = 0; j < 4; j++) acc[i][j] = zero4;

  s16x8 af[8], bf0[4], bf1[4];
  const int swr = (lr & 7) << 3;               // read-side XOR (shorts)

  auto stageA = [&](int sl, int h, int dt) {
    gll16(Abase + (size_t)(h * 128) * D_ + dt, &lA[sl][(h * 128 + wid * 16) * 64]);
    gll16(Abase + (size_t)(h * 128 + 8) * D_ + dt, &lA[sl][(h * 128 + wid * 16 + 8) * 64]);
  };
  auto stageB = [&](int sl, int h, int dt) {
    gll16(Bbase + (size_t)(h * 128) * D_ + dt, &lB[sl][(h * 128 + wid * 16) * 64]);
    gll16(Bbase + (size_t)(h * 128 + 8) * D_ + dt, &lB[sl][(h * 128 + wid * 16 + 8) * 64]);
  };
  // mh/nh are GLOBAL halves: rows mh*128 + wm*64 + mi*16 (+lr) all lie in
  // staging half mh; cols nh*128 + wn*32 + ni*16 (+lr) in staging half nh.
  auto readA = [&](int sl, int mh) {
#pragma unroll
    for (int mi = 0; mi < 4; mi++) {
      const int r = mh * 128 + wm * 64 + mi * 16 + lr;
#pragma unroll
      for (int ks = 0; ks < 2; ks++)
        af[mi * 2 + ks] = *(const s16x8*)&lA[sl][r * 64 + ((ks * 32 + g * 8) ^ swr)];
    }
  };
  auto readB = [&](int sl, int nh, s16x8* arr) {
#pragma unroll
    for (int ni = 0; ni < 2; ni++) {
      const int r = nh * 128 + wn * 32 + ni * 16 + lr;
#pragma unroll
      for (int ks = 0; ks < 2; ks++)
        arr[ni * 2 + ks] = *(const s16x8*)&lB[sl][r * 64 + ((ks * 32 + g * 8) ^ swr)];
    }
  };
  auto mmaq = [&](int mh, int nh, const s16x8* bb) {
    __builtin_amdgcn_s_setprio(1);
#pragma unroll
    for (int mi = 0; mi < 4; mi++)
#pragma unroll
      for (int ni = 0; ni < 2; ni++)
#pragma unroll
        for (int ks = 0; ks < 2; ks++)
          acc[mh * 4 + mi][nh * 2 + ni] = __builtin_amdgcn_mfma_f32_16x16x32_bf16(
              af[mi * 2 + ks], bb[ni * 2 + ks], acc[mh * 4 + mi][nh * 2 + ni], 0, 0, 0);
    __builtin_amdgcn_s_setprio(0);
  };

#define SYNC(N)                                            \
  asm volatile("s_waitcnt vmcnt(" #N ")" ::: "memory");    \
  __builtin_amdgcn_s_barrier();                            \
  asm volatile("" ::: "memory");

  // prologue: tile 0 -> slot 0, issue order A0,B0,B1,A1
  stageA(0, 0, 0); stageB(0, 0, 0); stageB(0, 1, 0); stageA(0, 1, 0);

  const int NT = D_ / 64;  // 32
  for (int t = 0; t < NT - 1; ++t) {
    const int s = t & 1, ns = s ^ 1;
    const int dtn = (t + 1) * 64;
    // P0: quadrant (mh0,nh0) — needs A0,B0 (the 4 oldest loads)
    SYNC(4)
    readA(s, 0); readB(s, 0, bf0);
    stageA(ns, 0, dtn);
    mmaq(0, 0, bf0);
    // P1: (mh0,nh1) — needs B1
    SYNC(4)
    readB(s, 1, bf1);
    stageB(ns, 0, dtn);
    mmaq(0, 1, bf1);
    // P2: (mh1,nh0) — needs A1
    SYNC(4)
    readA(s, 1);
    stageB(ns, 1, dtn);
    mmaq(1, 0, bf0);
    // P3: (mh1,nh1) — regs only, no sync
    stageA(ns, 1, dtn);
    mmaq(1, 1, bf1);
  }
  {  // peeled last tile, no prefetch
    const int s = (NT - 1) & 1;
    SYNC(4)
    readA(s, 0); readB(s, 0, bf0);
    mmaq(0, 0, bf0);
    SYNC(2)
    readB(s, 1, bf1);
    mmaq(0, 1, bf1);
    SYNC(0)
    readA(s, 1);
    mmaq(1, 0, bf0);
    mmaq(1, 1, bf1);
  }
#undef SYNC

  float bia[4];
#pragma unroll
  for (int nh = 0; nh < 2; nh++)
#pragma unroll
    for (int ni = 0; ni < 2; ni++)
      bia[nh * 2 + ni] = bias[col0 + nh * 128 + wn * 32 + ni * 16 + lr];
#pragma unroll
  for (int mh = 0; mh < 2; mh++)
#pragma unroll
    for (int mi = 0; mi < 4; mi++)
#pragma unroll
      for (int r = 0; r < 4; r++) {
        const int tg = row0 + mh * 128 + wm * 64 + mi * 16 + g * 4 + r;
        const float s = S[tg];
#pragma unroll
        for (int nh = 0; nh < 2; nh++)
#pragma unroll
          for (int ni = 0; ni < 2; ni++) {
            const int og = col0 + nh * 128 + wn * 32 + ni * 16 + lr;
            out[(size_t)tg * O_ + og] = acc[mh * 4 + mi][nh * 2 + ni][r] + bia[nh * 2 + ni] * s;
          }
      }
}

// ---------------------------------------------------------------------------
extern "C" void kernel_launch(void* const* d_in, const int* in_sizes, int n_in,
                              void* d_out, int out_size, void* d_ws, size_t ws_size,
                              hipStream_t stream) {
  const float* x    = (const float*)d_in[0];
  const float* comb = (const float*)d_in[1];
  const float* disp = (const float*)d_in[2];
  const float* w    = (const float*)d_in[3];
  const float* bias = (const float*)d_in[4];
  float* out = (float*)d_out;

  char* ws = (char*)d_ws;
  short* wT  = (short*)(ws);                    //  8,388,608 B  [O][D] bf16 (pre-swizzled)
  short* xdT = (short*)(ws + 8388608);          //  8,388,608 B  [B,E][I][C] bf16
  short* z   = (short*)(ws + 16777216);         // 67,108,864 B  [B][T][D] bf16 (pre-swizzled)
  float* xdF = (float*)(ws + 16777216);         // 16,777,216 B  aliases z (dead before zgemm)
  float* Se  = (float*)(ws + 83886080);         //    524,288 B  [B][E][T] f32
  float* S   = (float*)(ws + 84410368);         //     65,536 B  [B][T] f32

  hipMemsetAsync(xdF, 0, 16777216, stream);
  k_prep_wT<<<dim3(4096), dim3(256), 0, stream>>>(w, wT);
  k_gemm1<<<dim3(1024), dim3(256), 0, stream>>>(x, disp, xdF);
  k_cvt<<<dim3(4096), dim3(256), 0, stream>>>(xdF, xdT);
  k_zgemm<<<dim3(2048), dim3(256), 0, stream>>>(comb, xdT, z, Se);
  k_reduceS<<<dim3(64), dim3(256), 0, stream>>>(Se, S);
  k_outgemm<<<dim3(512), dim3(512), 0, stream>>>(z, wT, bias, S, out);
}